// Round 6
// baseline (247.238 us; speedup 1.0000x reference)
//
#include <hip/hip_runtime.h>
#include <stdint.h>

#define CIN 256
#define COUT 256
#define RANK 64
#define H_ 112
#define W_ 112
#define HW_ (112*112)

typedef short bf16x8 __attribute__((ext_vector_type(8)));   // 8 bf16 = 4 VGPRs
typedef float f32x4 __attribute__((ext_vector_type(4)));

// byte-offset swizzle for the y2 slab ([w'] stride 128 B): XOR bits 4-6 with w'&7
#define SWZ(a) ((a) ^ ((((a) >> 7) & 7) << 4))

// round-to-nearest-even fp32 -> bf16, packed pair
__device__ __forceinline__ unsigned rne2(float a, float b){
  unsigned ua = __builtin_bit_cast(unsigned, a);
  unsigned ub = __builtin_bit_cast(unsigned, b);
  ua += 0x7FFFu + ((ua >> 16) & 1u);
  ub += 0x7FFFu + ((ub >> 16) & 1u);
  return (ua >> 16) | (ub & 0xFFFF0000u);
}
__device__ __forceinline__ unsigned short rne1(float a){
  unsigned ua = __builtin_bit_cast(unsigned, a);
  ua += 0x7FFFu + ((ua >> 16) & 1u);
  return (unsigned short)(ua >> 16);
}

// ---- K_pre1: blocks [0, nb*456): x NCHW fp32 -> xt bf16 [lb][hh 114][i0p 4][g8 8][w 112][c 8]
//              (one 64-channel pass per block: bid -> (lb, hh, i0p))
//              blocks [nb*456, +256): w_sum[o][i] = sum_k w_head[k][o][i]  (chunk 0 only)
__global__ __launch_bounds__(256) void k_pre1(const float* __restrict__ x,
                                              unsigned short* __restrict__ xt,
                                              const float* __restrict__ wh,
                                              float* __restrict__ wsum,
                                              int base_b, int nb){
  __shared__ float ldsf[64*120];
  const int tid = threadIdx.x;
  if (blockIdx.x >= (unsigned)(nb*456)){
    int o = blockIdx.x - nb*456;
    float s = 0.f;
    for (int k = 0; k < RANK; ++k) s += wh[(k*COUT + o)*CIN + tid];
    wsum[o*CIN + tid] = s;
    return;
  }
  const int lb  = blockIdx.x / 456;
  const int rem = blockIdx.x % 456;
  const int hh  = rem >> 2, i0p = rem & 3;
  const int bb  = base_b + lb;
  const int h   = hh - 1;
  unsigned short* dst = xt + ((size_t)(lb*114 + hh))*28672 + (size_t)i0p*7168;

  if (h < 0 || h >= H_){
    uint4 z = {0,0,0,0};
    for (int ck = tid; ck < 896; ck += 256)
      *(uint4*)(dst + ck*8) = z;
    return;
  }

  // stage 64 channels x 112 w fp32, coalesced float4
  {
    int c = tid / 28, wq = tid % 28;
    #pragma unroll
    for (int j = 0; j < 7; ++j){
      const float4 v = *(const float4*)(x + ((size_t)(bb*CIN + i0p*64 + c))*HW_ + h*W_ + wq*4);
      *(float4*)&ldsf[c*120 + wq*4] = v;
      wq += 4; c += 9; if (wq >= 28){ wq -= 28; c += 1; }
    }
  }
  __syncthreads();
  for (int ck = tid; ck < 896; ck += 256){
    int g8 = ck / 112, w = ck % 112;
    const float* src = &ldsf[(g8*8)*120 + w];
    uint4 st;
    st.x = rne2(src[0],     src[120]);
    st.y = rne2(src[240],   src[360]);
    st.z = rne2(src[480],   src[600]);
    st.w = rne2(src[720],   src[840]);
    *(uint4*)(dst + ck*8) = st;
  }
}

// ---- K_pre2: blocks [0,192): w_eff[dh][r][i] (bf16); blocks [192,448): wtp[o][dw][r] (bf16)
__global__ __launch_bounds__(256) void k_pre2(const float* __restrict__ wb,
                                              const float* __restrict__ wsum,
                                              unsigned short* __restrict__ weff,
                                              const float* __restrict__ wt,
                                              unsigned short* __restrict__ wtp){
  const int tid = threadIdx.x;
  if (blockIdx.x < 192){
    int bid = blockIdx.x;            // dh*64 + r
    int dh = bid >> 6, r = bid & 63;
    float s = 0.f;
    for (int o = 0; o < COUT; ++o)
      s += wb[(r*COUT + o)*3 + dh] * wsum[o*CIN + tid];
    weff[bid*CIN + tid] = rne1(s);
  } else {
    int o = blockIdx.x - 192;
    if (tid < 192){
      int dw = tid >> 6, r = tid & 63;
      wtp[o*192 + tid] = rne1(wt[(o*RANK + r)*3 + dw]);
    }
  }
}

// ---- K_fused: body GEMM (4 h/block, 64 r/wave) -> swizzled LDS y2 -> tail GEMM -> out ----
// Grid nb*28 blocks (lb, h-quad), 256 threads / 4 waves. Wave wid owns h = h0+wid.
__global__ __launch_bounds__(256,2) void k_fused(const unsigned short* __restrict__ xt,
                                                 const unsigned short* __restrict__ weff,
                                                 const unsigned short* __restrict__ wtp,
                                                 const float* __restrict__ bias,
                                                 float* __restrict__ out,
                                                 int base_b){
  // phase A: 6 rows x 3584 ushorts = 43008 B; phase B/C: y2 slab 4*114*128 B = 58368 B
  __shared__ alignas(16) unsigned short lds[29184];
  const int tid  = threadIdx.x;
  const int wid  = tid >> 6, lane = tid & 63, g = lane >> 4, l15 = lane & 15;
  const int lb   = blockIdx.x / 28, hb = blockIdx.x % 28;
  const int bb   = base_b + lb;
  const int h0   = hb*4;

  // ---- phase A: body GEMM, K = 8 steps x 32 channels ----
  f32x4 acc[4][7];
  #pragma unroll
  for (int a = 0; a < 4; ++a)
    #pragma unroll
    for (int b = 0; b < 7; ++b) acc[a][b] = (f32x4){0.f,0.f,0.f,0.f};

  uint4 sv[11];
  // staging: 2688 uint4 chunks = 6 rows x 448; chunk -> (row = c/448, off = c%448)
  auto load_step = [&](int i0){
    #pragma unroll
    for (int j = 0; j < 11; ++j){
      int cid = tid + 256*j;
      if (cid < 2688){
        int row = cid / 448, off = cid % 448;
        sv[j] = *(const uint4*)(xt + ((size_t)((lb*114 + h0 + row)*8 + i0))*3584 + off*8);
      }
    }
  };
  auto write_step = [&](){
    #pragma unroll
    for (int j = 0; j < 11; ++j){
      int cid = tid + 256*j;
      if (cid < 2688){
        int row = cid / 448, off = cid % 448;
        *(uint4*)(lds + row*3584 + off*8) = sv[j];
      }
    }
  };
  auto compute = [&](int i0){
    #pragma unroll
    for (int dh = 0; dh < 3; ++dh){
      bf16x8 af[4];
      const unsigned short* ab = weff + (size_t)(dh*64 + l15)*CIN + i0*32 + g*8;
      #pragma unroll
      for (int rt = 0; rt < 4; ++rt)
        af[rt] = *(const bf16x8*)(ab + rt*16*CIN);
      const unsigned short* qb = lds + (wid + dh)*3584 + g*896 + l15*8;
      #pragma unroll
      for (int wt = 0; wt < 7; ++wt){
        bf16x8 bfv = *(const bf16x8*)(qb + wt*128);
        #pragma unroll
        for (int rt = 0; rt < 4; ++rt)
          acc[rt][wt] = __builtin_amdgcn_mfma_f32_16x16x32_bf16(af[rt], bfv, acc[rt][wt], 0, 0, 0);
      }
    }
  };

  load_step(0);
  for (int t = 0; t < 8; ++t){
    __syncthreads();                 // buffer free (previous compute done)
    write_step();
    __syncthreads();                 // staged data visible
    if (t < 7) load_step(t+1);       // issue next-step loads; compute hides latency (T14)
    compute(t);
  }
  __syncthreads();

  // ---- phase B: acc -> swizzled y2 slab [4 h][114 w'][64 r] bf16, w' = w+1 ----
  unsigned char* y2b = (unsigned char*)lds;
  if (tid < 64){                     // zero halo columns w'=0,113 for all 4 h
    int hz = tid >> 4, wsel = (tid >> 3) & 1, q = tid & 7;
    unsigned a = (unsigned)(hz*14592 + (wsel ? 113 : 0)*128 + q*16);
    *(uint4*)(y2b + SWZ(a)) = (uint4){0,0,0,0};
  }
  #pragma unroll
  for (int wt = 0; wt < 7; ++wt){
    #pragma unroll
    for (int rt = 0; rt < 4; ++rt){
      unsigned lo = rne2(acc[rt][wt][0], acc[rt][wt][1]);
      unsigned hi = rne2(acc[rt][wt][2], acc[rt][wt][3]);
      uint2 st; st.x = lo; st.y = hi;
      unsigned a = (unsigned)(wid*14592 + (wt*16 + l15 + 1)*128 + rt*32 + g*8);
      *(uint2*)(y2b + SWZ(a)) = st;
    }
  }
  __syncthreads();

  // ---- phase C: tail GEMM; wave wid owns h = h0+wid, loops 4 o-blocks of 64 ----
  #pragma unroll
  for (int opass = 0; opass < 4; ++opass){
    const int obase = opass*64;
    f32x4 a2[4][7];
    #pragma unroll
    for (int a = 0; a < 4; ++a)
      #pragma unroll
      for (int b = 0; b < 7; ++b) a2[a][b] = (f32x4){0.f,0.f,0.f,0.f};

    #pragma unroll
    for (int s = 0; s < 6; ++s){       // k-step: dw = s>>1, r-half = s&1
      bf16x8 af[4];
      const unsigned short* ab = wtp + (size_t)(obase + l15)*192 + s*32 + g*8;
      #pragma unroll
      for (int rt = 0; rt < 4; ++rt)
        af[rt] = *(const bf16x8*)(ab + rt*16*192);
      #pragma unroll
      for (int wt = 0; wt < 7; ++wt){
        unsigned a = (unsigned)(wid*14592 + (wt*16 + l15 + (s>>1))*128 + (s&1)*64 + g*16);
        bf16x8 bv = *(const bf16x8*)(y2b + SWZ(a));
        #pragma unroll
        for (int rt = 0; rt < 4; ++rt)
          a2[rt][wt] = __builtin_amdgcn_mfma_f32_16x16x32_bf16(af[rt], bv, a2[rt][wt], 0, 0, 0);
      }
    }

    float* ob = out + ((size_t)(bb*COUT) + obase)*HW_ + (h0 + wid)*W_;
    #pragma unroll
    for (int rt = 0; rt < 4; ++rt){
      #pragma unroll
      for (int ii = 0; ii < 4; ++ii){
        float bvv = bias[obase + rt*16 + g*4 + ii];
        #pragma unroll
        for (int wt = 0; wt < 7; ++wt)
          ob[(size_t)(rt*16 + g*4 + ii)*HW_ + wt*16 + l15] = a2[rt][wt][ii] + bvv;
      }
    }
  }
}

extern "C" void kernel_launch(void* const* d_in, const int* in_sizes, int n_in,
                              void* d_out, int out_size, void* d_ws, size_t ws_size,
                              hipStream_t stream) {
  const float* x      = (const float*)d_in[0];
  const float* w_head = (const float*)d_in[1];
  const float* w_body = (const float*)d_in[2];
  const float* w_tail = (const float*)d_in[3];
  const float* b_tail = (const float*)d_in[4];
  float* out = (float*)d_out;
  char* ws = (char*)d_ws;

  // ws layout: wsum fp32 @0 (262144 B); weff bf16 @262144 (98304 B);
  // wtp bf16 @360448 (98304 B); xt chunk buffer @458752.
  float*          wsum = (float*)ws;
  unsigned short* weff = (unsigned short*)(ws + 262144);
  unsigned short* wtp  = (unsigned short*)(ws + 360448);
  unsigned short* xt   = (unsigned short*)(ws + 458752);

  const size_t XT_PER_B = (size_t)114 * 57344;           // 6,537,216 B per batch
  size_t avail = (ws_size > 458752) ? ws_size - 458752 : 0;
  int chunk_b = (int)(avail / XT_PER_B);
  if (chunk_b > 16) chunk_b = 16;
  if (chunk_b < 1)  chunk_b = 1;                         // ws proven >= 26.1 MB, so >= 3
  int nchunks = (16 + chunk_b - 1) / chunk_b;

  int base = 0;
  for (int c = 0; c < nchunks; ++c){
    int remaining = 16 - base;
    int nb = (remaining + (nchunks - c) - 1) / (nchunks - c);   // balanced split
    k_pre1<<<nb*456 + (c == 0 ? 256 : 0), 256, 0, stream>>>(x, xt, w_head, wsum, base, nb);
    if (c == 0)
      k_pre2<<<448, 256, 0, stream>>>(w_body, wsum, weff, w_tail, wtp);
    k_fused<<<nb*28, 256, 0, stream>>>(xt, weff, wtp, b_tail, out, base);
    base += nb;
  }
}